// Round 16
// baseline (246.458 us; speedup 1.0000x reference)
//
#include <hip/hip_runtime.h>
#include <hip/hip_fp16.h>

#define D_IN   128
#define HEADS  8
#define FOUT   64
#define NOUT   16     // 8 src + 8 trg folded outputs
#define NPB    512    // nodes per bin (local index 9 bits; src 20 + local 9 = 29 bits)
#define NPB_SH 9
#define NB_MAX 512    // max bins (block-internal scans are 512-wide)
#define CHUNK  8192   // edges per histogram/scatter block (~42 edges/bin/block -> full lines)
#define NBLK_MAX 1024
#define TPN    8      // threads per node in k_nodesum
#define SROWS  64     // nodes per k_scores tile
#define SPAD   129    // padded LDS row stride (floats)
#define DET_BLOCKS 128

typedef unsigned __attribute__((ext_vector_type(2))) uint2v;
typedef float    __attribute__((ext_vector_type(4))) float4v;

// -------------------------------- helpers -----------------------------------
__device__ __forceinline__ unsigned pack2(float a, float b) {
    union { __half2 h; unsigned u; } c;
    c.h = __floats2half2_rn(a, b);
    return c.u;
}
__device__ __forceinline__ float2 up2(unsigned u) {
    union { unsigned x; __half2 h; } c;
    c.x = u;
    return __half22float2(c.h);
}

// Non-temporal ONLY for dense read-once (idx, x) and dense write-once (out)
// streams. NEVER for scattered stores or producer->consumer intermediates
// (r8: nt scattered stores defeat L2 write-combining, 13->89 MB writes).
__device__ __forceinline__ unsigned ntl_u(const unsigned* p) {
    return __builtin_nontemporal_load(p);
}
__device__ __forceinline__ uint2v ntl_u2(const unsigned* p) {
    return __builtin_nontemporal_load((const uint2v*)p);
}
__device__ __forceinline__ float4v ntl_f4(const float* p) {
    return __builtin_nontemporal_load((const float4v*)p);
}
__device__ __forceinline__ void nts_f4(float* p, float4v v) {
    __builtin_nontemporal_store(v, (float4v*)p);
}

__device__ __forceinline__ void load_edge(const unsigned int* idx, int e, int E,
                                          bool is64, unsigned int& s, unsigned int& t) {
    if (is64) {
        uint2v a = ntl_u2(idx + 2 * (size_t)e);
        uint2v b = ntl_u2(idx + 2 * ((size_t)E + e));
        s = a.x; t = b.x;
    } else {
        s = ntl_u(idx + e);
        t = ntl_u(idx + (size_t)E + e);
    }
}

// ---------------------------------------------------------------------------
// Fold scoring vectors into projection (Wc [16][128]); zero flag + binTotal.
// (A 4B hipMemsetAsync cost ~60us/replay as a fillBufferAligned dispatch - r7.)
__global__ void k_fold_w(const float* __restrict__ W,
                         const float* __restrict__ a_src,
                         const float* __restrict__ a_trg,
                         float* __restrict__ Wc,
                         unsigned int* __restrict__ flag,
                         int* __restrict__ binTotal, int NB) {
    int t = blockIdx.x * blockDim.x + threadIdx.x;
    if (t == 0) flag[0] = 0u;
    if (binTotal && t < NB) binTotal[t] = 0;
    if (t >= D_IN * HEADS) return;
    int d = t >> 3, h = t & 7;
    const float* wrow = W + d * (HEADS * FOUT) + h * FOUT;
    float s1 = 0.f, s2 = 0.f;
    #pragma unroll 4
    for (int f = 0; f < FOUT; ++f) {
        float w = wrow[f];
        s1 += w * a_src[h * FOUT + f];
        s2 += w * a_trg[h * FOUT + f];
    }
    Wc[h * D_IN + d]           = s1;
    Wc[(HEADS + h) * D_IN + d] = s2;
}

// ---------------------------------------------------------------------------
// FUSED: per-node scores (shuffle-free, r7) + per-chunk histogram (blocks
// < NBLK) + sampled global int64/int32 detection (blocks < DET_BLOCKS).
// Hist decides the layout BLOCK-LOCALLY from the first 64 odd words of idx
// (all zero <=> int64 high-halves), so hist's idx read overlaps scores' x read.
__global__ void k_scores_h(const float* __restrict__ x,
                           const float* __restrict__ Wc,
                           float* __restrict__ strg_f,
                           __half* __restrict__ ssrc_h, int N,
                           const unsigned int* __restrict__ idx, int E,
                           int dwords, unsigned int* __restrict__ flag,
                           int* __restrict__ histB, int NB, int NBLK,
                           int* __restrict__ binTotal) {
    int tid = threadIdx.x;

    // --- global detection sample (for later kernels: scatter, edge_out) ---
    if ((int)blockIdx.x < DET_BLOCKS) {
        unsigned int local = 0;
        int stride = DET_BLOCKS * 256;
        for (int i = blockIdx.x * 256 + tid; 2 * i + 1 < dwords; i += stride)
            local |= idx[2 * i + 1];
        if (__any(local != 0) && (tid & 63) == 0)
            atomicOr(flag, 1u);
    }

    // --- histogram chunk (blocks < NBLK); barriers are block-uniform ------
    if ((int)blockIdx.x < NBLK) {
        __shared__ int h[NB_MAX];
        __shared__ int s_i32;
        if (tid == 0) s_i32 = 0;
        for (int i = tid; i < NB; i += blockDim.x) h[i] = 0;
        __syncthreads();
        if (tid < 64) {
            unsigned int v = (2 * tid + 1 < 2 * E) ? idx[2 * tid + 1] : 0u;
            if (__any(v != 0) && tid == 0) s_i32 = 1;
        }
        __syncthreads();
        bool is64 = (s_i32 == 0);

        int base = blockIdx.x * CHUNK;
        int lim  = min(base + CHUNK, E);
        for (int e = base + tid; e < lim; e += blockDim.x) {
            unsigned int t = is64 ? ntl_u2(idx + 2 * ((size_t)E + e)).x
                                  : ntl_u(idx + (size_t)E + e);
            atomicAdd(&h[t >> NPB_SH], 1);
        }
        __syncthreads();
        for (int i = tid; i < NB; i += blockDim.x) {
            histB[(size_t)i * NBLK + blockIdx.x] = h[i];
            if (h[i]) atomicAdd(&binTotal[i], h[i]);
        }
        __syncthreads();
    }

    // --- per-node scores --------------------------------------------------
    __shared__ float xt[SROWS * SPAD];
    int node0 = blockIdx.x * SROWS;
    int nrows = min(SROWS, N - node0);
    if (nrows <= 0) return;

    for (int i = tid; i < nrows * 32; i += 256) {
        int r = i >> 5, c = (i & 31) * 4;
        float4v v = ntl_f4(x + (size_t)(node0 + r) * D_IN + c);
        float* dst = &xt[r * SPAD + c];
        dst[0] = v.x; dst[1] = v.y; dst[2] = v.z; dst[3] = v.w;
    }
    __syncthreads();

    int r  = tid & 63;
    int og = tid >> 6;          // wave-uniform output group (4 outputs)
    if (r >= nrows) return;
    int n = node0 + r;

    const float* w = Wc + og * 4 * D_IN;
    float a0 = 0.f, a1 = 0.f, a2 = 0.f, a3 = 0.f;
    const float* xr = &xt[r * SPAD];
    #pragma unroll 8
    for (int d = 0; d < D_IN; ++d) {
        float xv = xr[d];
        a0 += xv * w[d];
        a1 += xv * w[D_IN + d];
        a2 += xv * w[2 * D_IN + d];
        a3 += xv * w[3 * D_IN + d];
    }

    if (og < 2) {
        uint2 hp;
        hp.x = pack2(a0, a1);
        hp.y = pack2(a2, a3);
        *(uint2*)(ssrc_h + (size_t)n * HEADS + og * 4) = hp;
    } else {
        *(float4*)(strg_f + (size_t)n * HEADS + (og - 2) * 4) =
            make_float4(a0, a1, a2, a3);
    }
}

// ---------------------------------------------------------------------------
// Pass C (self-scanning): scatter packed edge records into bin order.
// The k_scan dispatch is gone: each block recomputes (a) the exclusive
// bin-base scan of binTotal (512-wide LDS Hillis-Steele, NB<=512) and
// (b) its own block-offset per bin by summing histB[i][0..b-1] (L2-hot,
// <=390 adds per bin, one bin per thread). record = src|(trg&511)<<20.
__global__ void k_scatter(const unsigned int* __restrict__ idx, int E,
                          const unsigned int* __restrict__ flag,
                          const int* __restrict__ histB, int NB, int NBLK,
                          const int* __restrict__ binTotal,
                          unsigned int* __restrict__ binned) {
    __shared__ int cnt[NB_MAX];
    __shared__ int sc[512];
    int b   = blockIdx.x;
    int tid = threadIdx.x;

    sc[tid] = (tid < NB) ? binTotal[tid] : 0;
    __syncthreads();
    #pragma unroll
    for (int off = 1; off < 512; off <<= 1) {
        int t = (tid >= off) ? sc[tid - off] : 0;
        __syncthreads();
        sc[tid] += t;
        __syncthreads();
    }
    if (tid < NB) {
        int o = 0;
        const int* row = histB + (size_t)tid * NBLK;
        for (int j = 0; j < b; ++j) o += row[j];
        cnt[tid] = (tid ? sc[tid - 1] : 0) + o;
    }
    __syncthreads();

    bool is64 = (*flag == 0u);
    int base = b * CHUNK;
    int lim  = min(base + CHUNK, E);
    for (int e = base + tid; e < lim; e += blockDim.x) {
        unsigned int s, t;
        load_edge(idx, e, E, is64, s, t);
        int pos = atomicAdd(&cnt[t >> NPB_SH], 1);
        binned[pos] = s | ((t & (NPB - 1u)) << 20);
    }
}

// Pass D (self-scanning): per-bin counting sort by low 9 target bits -> CSR.
// binBase computed in-block (LDS atomic reduce of binTotal[0..b-1]).
// 1024 threads; not fused with nodesum (r11: 196-block fusion -> 14% occ).
__global__ void k_sort2(const unsigned int* __restrict__ binned,
                        const int* __restrict__ binTotal,
                        unsigned int* __restrict__ sortedSrc,
                        int* __restrict__ rowPtr, int N, int NB) {
    __shared__ int cnt[NPB];
    __shared__ int scn[NPB];
    __shared__ int s_base;
    int b = blockIdx.x;
    int node0 = b << NPB_SH;
    int i = threadIdx.x;
    int T = blockDim.x;

    if (i == 0) s_base = 0;
    if (i < NPB) cnt[i] = 0;
    __syncthreads();
    if (i < b) atomicAdd(&s_base, binTotal[i]);
    __syncthreads();
    int start = s_base;
    int total = binTotal[b];

    for (int e = i; e < total; e += T)
        atomicAdd(&cnt[binned[start + e] >> 20], 1);
    __syncthreads();

    if (i < NPB) scn[i] = cnt[i];
    __syncthreads();
    for (int o = 1; o < NPB; o <<= 1) {
        int t = (i < NPB && i >= o) ? scn[i - o] : 0;
        __syncthreads();
        if (i < NPB) scn[i] += t;
        __syncthreads();
    }
    if (i < NPB) {
        int excl = scn[i] - cnt[i];
        cnt[i] = excl;
        int n = node0 + i;
        if (n < N) rowPtr[n] = start + excl;
    }
    if (b == NB - 1 && i == 0) rowPtr[N] = start + total;
    __syncthreads();

    for (int e = i; e < total; e += T) {
        unsigned int v = binned[start + e];
        int pos = atomicAdd(&cnt[v >> 20], 1);
        sortedSrc[start + pos] = v & 0xFFFFFu;
    }
}

// ---------------------------------------------------------------------------
// Pass E: per-node sums via contiguous edge runs (full-occupancy grid);
// emits fused combo record { strg half[8], 1/sum half[8] }.
__global__ void k_nodesum(const unsigned int* __restrict__ sortedSrc,
                          const int* __restrict__ rowPtr,
                          const __half* __restrict__ ssrc_h,
                          const float* __restrict__ strg_f,
                          __half* __restrict__ combo, int N) {
    int gt = blockIdx.x * blockDim.x + threadIdx.x;
    int n  = gt >> 3;           // TPN = 8
    int k  = gt & (TPN - 1);
    if (n >= N) return;

    int r0 = rowPtr[n], r1 = rowPtr[n + 1];
    const float4* tp = (const float4*)(strg_f + (size_t)n * HEADS);
    float4 ta = tp[0], tb = tp[1];
    float st[8] = { ta.x, ta.y, ta.z, ta.w, tb.x, tb.y, tb.z, tb.w };
    float acc[8] = { 0, 0, 0, 0, 0, 0, 0, 0 };

    for (int e = r0 + k; e < r1; e += TPN) {
        unsigned int s = sortedSrc[e];
        uint4 sv = *(const uint4*)(ssrc_h + (size_t)s * HEADS);
        float2 f01 = up2(sv.x), f23 = up2(sv.y), f45 = up2(sv.z), f67 = up2(sv.w);
        float vs[8] = { f01.x, f01.y, f23.x, f23.y, f45.x, f45.y, f67.x, f67.y };
        #pragma unroll
        for (int h = 0; h < HEADS; ++h) {
            float sc = vs[h] + st[h];
            sc = sc > 0.f ? sc : 0.2f * sc;
            acc[h] += expf(sc);
        }
    }
    #pragma unroll
    for (int h = 0; h < HEADS; ++h) {
        acc[h] += __shfl_xor(acc[h], 1, 64);
        acc[h] += __shfl_xor(acc[h], 2, 64);
        acc[h] += __shfl_xor(acc[h], 4, 64);
    }
    if (k == 0) {
        float rs[8];
        #pragma unroll
        for (int h = 0; h < HEADS; ++h) rs[h] = 1.0f / (acc[h] + 1e-16f);
        uint4 c0, c1;
        c0.x = pack2(st[0], st[1]);  c0.y = pack2(st[2], st[3]);
        c0.z = pack2(st[4], st[5]);  c0.w = pack2(st[6], st[7]);
        c1.x = pack2(rs[0], rs[1]);  c1.y = pack2(rs[2], rs[3]);
        c1.z = pack2(rs[4], rs[5]);  c1.w = pack2(rs[6], rs[7]);
        uint4* cp = (uint4*)(combo + (size_t)n * 16);
        cp[0] = c0;
        cp[1] = c1;
    }
}

// ---------------------------------------------------------------------------
// Fast edge output (r12 single-edge form: measured 65.1us; both dual-edge
// variants regressed - r10: 67, r15: 66.5. One edge per thread, max TLP):
// 2 gathers (16B ssrc_h, 32B combo) over a 4.8 MB hot set; nt idx/out.
__global__ void k_edge_out_c(const unsigned int* __restrict__ idx, int E,
                             const __half* __restrict__ ssrc_h,
                             const __half* __restrict__ combo,
                             const unsigned int* __restrict__ flag,
                             float* __restrict__ out) {
    int e = blockIdx.x * blockDim.x + threadIdx.x;
    if (e >= E) return;
    bool is64 = (*flag == 0u);
    unsigned int s, t;
    load_edge(idx, e, E, is64, s, t);

    uint4 sv = *(const uint4*)(ssrc_h + (size_t)s * HEADS);
    const uint4* cp = (const uint4*)(combo + (size_t)t * 16);
    uint4 c0 = cp[0], c1 = cp[1];

    float2 s01 = up2(sv.x), s23 = up2(sv.y), s45 = up2(sv.z), s67 = up2(sv.w);
    float2 t01 = up2(c0.x), t23 = up2(c0.y), t45 = up2(c0.z), t67 = up2(c0.w);
    float2 r01 = up2(c1.x), r23 = up2(c1.y), r45 = up2(c1.z), r67 = up2(c1.w);

    float ss[8] = { s01.x, s01.y, s23.x, s23.y, s45.x, s45.y, s67.x, s67.y };
    float st[8] = { t01.x, t01.y, t23.x, t23.y, t45.x, t45.y, t67.x, t67.y };
    float rs[8] = { r01.x, r01.y, r23.x, r23.y, r45.x, r45.y, r67.x, r67.y };

    float o[8];
    #pragma unroll
    for (int h = 0; h < HEADS; ++h) {
        float sc = ss[h] + st[h];
        sc = sc > 0.f ? sc : 0.2f * sc;
        o[h] = expf(sc) * rs[h];
    }
    float4v o0 = { o[0], o[1], o[2], o[3] };
    float4v o1 = { o[4], o[5], o[6], o[7] };
    nts_f4(out + (size_t)e * HEADS,     o0);
    nts_f4(out + (size_t)e * HEADS + 4, o1);
}

// ---------------------------------------------------------------------------
// Fallback path (device atomics + fp32), used only if workspace too small.
__device__ __forceinline__ void edge_scores(const float* ssrc, const float* strg,
                                            unsigned int s, unsigned int t, float* ex) {
    const float4* sp = (const float4*)(ssrc + (size_t)s * HEADS);
    const float4* tp = (const float4*)(strg + (size_t)t * HEADS);
    float4 sa = sp[0], sb = sp[1], ta = tp[0], tb = tp[1];
    float v[8] = { sa.x + ta.x, sa.y + ta.y, sa.z + ta.z, sa.w + ta.w,
                   sb.x + tb.x, sb.y + tb.y, sb.z + tb.z, sb.w + tb.w };
    #pragma unroll
    for (int h = 0; h < HEADS; ++h) {
        float sc = v[h];
        sc = sc > 0.f ? sc : 0.2f * sc;
        ex[h] = expf(sc);
    }
}

__global__ void k_detect_fb(const unsigned int* __restrict__ idx_w, int nwords,
                            unsigned int* __restrict__ flag) {
    unsigned int local = 0;
    int stride = gridDim.x * blockDim.x;
    for (int i = blockIdx.x * blockDim.x + threadIdx.x; 2 * i + 1 < nwords; i += stride)
        local |= idx_w[2 * i + 1];
    if (__any(local != 0) && (threadIdx.x & 63) == 0)
        atomicOr(flag, 1u);
}

__global__ void k_scores_fb(const float* __restrict__ x,
                            const float* __restrict__ Wc,
                            float* __restrict__ ssrc_f,
                            float* __restrict__ strg_f, int N) {
    __shared__ float xt[SROWS * SPAD];
    int node0 = blockIdx.x * SROWS;
    int tid   = threadIdx.x;
    int nrows = min(SROWS, N - node0);

    for (int i = tid; i < nrows * 32; i += 256) {
        int r = i >> 5, c = (i & 31) * 4;
        float4v v = ntl_f4(x + (size_t)(node0 + r) * D_IN + c);
        float* dst = &xt[r * SPAD + c];
        dst[0] = v.x; dst[1] = v.y; dst[2] = v.z; dst[3] = v.w;
    }
    __syncthreads();

    int r  = tid & 63;
    int og = tid >> 6;
    if (r >= nrows) return;
    int n = node0 + r;

    const float* w = Wc + og * 4 * D_IN;
    float a0 = 0.f, a1 = 0.f, a2 = 0.f, a3 = 0.f;
    const float* xr = &xt[r * SPAD];
    #pragma unroll 8
    for (int d = 0; d < D_IN; ++d) {
        float xv = xr[d];
        a0 += xv * w[d];
        a1 += xv * w[D_IN + d];
        a2 += xv * w[2 * D_IN + d];
        a3 += xv * w[3 * D_IN + d];
    }
    float4 res = make_float4(a0, a1, a2, a3);
    if (og < 2) *(float4*)(ssrc_f + (size_t)n * HEADS + og * 4)       = res;
    else        *(float4*)(strg_f + (size_t)n * HEADS + (og - 2) * 4) = res;
}

__global__ void k_edge_sum(const unsigned int* __restrict__ idx, int E,
                           const float* __restrict__ ssrc,
                           const float* __restrict__ strg,
                           float* __restrict__ sums,
                           const unsigned int* __restrict__ flag) {
    int e = blockIdx.x * blockDim.x + threadIdx.x;
    if (e >= E) return;
    bool is64 = (*flag == 0u);
    unsigned int s, t;
    load_edge(idx, e, E, is64, s, t);
    float ex[8];
    edge_scores(ssrc, strg, s, t, ex);
    float* dst = sums + (size_t)t * HEADS;
    #pragma unroll
    for (int h = 0; h < HEADS; ++h)
        atomicAdd(dst + h, ex[h]);
}

__global__ void k_edge_out(const unsigned int* __restrict__ idx, int E,
                           const float* __restrict__ ssrc,
                           const float* __restrict__ strg,
                           const float* __restrict__ sums,
                           const unsigned int* __restrict__ flag,
                           float* __restrict__ out) {
    int e = blockIdx.x * blockDim.x + threadIdx.x;
    if (e >= E) return;
    bool is64 = (*flag == 0u);
    unsigned int s, t;
    load_edge(idx, e, E, is64, s, t);
    float ex[8];
    edge_scores(ssrc, strg, s, t, ex);
    const float4* sm = (const float4*)(sums + (size_t)t * HEADS);
    float4 m0 = sm[0], m1 = sm[1];
    float4 o0, o1;
    o0.x = ex[0] / (m0.x + 1e-16f);  o0.y = ex[1] / (m0.y + 1e-16f);
    o0.z = ex[2] / (m0.z + 1e-16f);  o0.w = ex[3] / (m0.w + 1e-16f);
    o1.x = ex[4] / (m1.x + 1e-16f);  o1.y = ex[5] / (m1.y + 1e-16f);
    o1.z = ex[6] / (m1.z + 1e-16f);  o1.w = ex[7] / (m1.w + 1e-16f);
    float4* op = (float4*)(out + (size_t)e * HEADS);
    op[0] = o0;
    op[1] = o1;
}

// ---------------------------------------------------------------------------
extern "C" void kernel_launch(void* const* d_in, const int* in_sizes, int n_in,
                              void* d_out, int out_size, void* d_ws, size_t ws_size,
                              hipStream_t stream) {
    const float*        x     = (const float*)d_in[0];
    const float*        W     = (const float*)d_in[1];
    const float*        a_src = (const float*)d_in[2];
    const float*        a_trg = (const float*)d_in[3];
    const unsigned int* idx   = (const unsigned int*)d_in[4];

    const int N  = in_sizes[0] / D_IN;   // 100000
    const int E  = in_sizes[4] / 2;      // 3200000
    const int NH = N * HEADS;
    const int NB   = (N + NPB - 1) / NPB;     // 196
    const int NBLK = (E + CHUNK - 1) / CHUNK; // 391

    float* out = (float*)d_out;
    char*  ws  = (char*)d_ws;
    size_t NHb = (size_t)NH * sizeof(float);

    // ---- fast-path layout -------------------------------------------------
    size_t off = 0;
    auto alloc = [&](size_t bytes) { size_t o = off; off = (off + bytes + 255) & ~(size_t)255; return o; };
    unsigned int* flag     = (unsigned int*)(ws + alloc(8));
    float*        strg_f   = (float*)(ws + alloc(NHb));
    __half*       ssrc_h   = (__half*)(ws + alloc((size_t)NH * sizeof(__half)));
    __half*       combo    = (__half*)(ws + alloc((size_t)N * 16 * sizeof(__half)));
    float*        Wc       = (float*)(ws + alloc(NOUT * D_IN * sizeof(float)));
    int*          histB    = (int*)(ws + alloc((size_t)NB * NBLK * sizeof(int)));
    int*          binTotal = (int*)(ws + alloc((size_t)NB * sizeof(int)));
    unsigned int* binned   = (unsigned int*)(ws + alloc((size_t)E * sizeof(unsigned int)));
    unsigned int* sortedS  = (unsigned int*)(ws + alloc((size_t)E * sizeof(unsigned int)));
    int*          rowPtr   = (int*)(ws + alloc((size_t)(N + 1) * sizeof(int)));

    const bool fast = (off <= ws_size) && (NB <= NB_MAX) && (NBLK <= NBLK_MAX)
                      && (N < (1 << 20));

    int dwords = in_sizes[4];
    if (dwords > (1 << 20)) dwords = 1 << 20;   // sampled detection is sufficient

    if (fast) {
        k_fold_w <<<(D_IN * HEADS + 255) / 256, 256, 0, stream>>>(W, a_src, a_trg, Wc,
                                                                  flag, binTotal, NB);
        k_scores_h <<<(N + SROWS - 1) / SROWS, 256, 0, stream>>>(x, Wc, strg_f,
                                                                 ssrc_h, N, idx, E,
                                                                 dwords, flag,
                                                                 histB, NB, NBLK,
                                                                 binTotal);
        k_scatter <<<NBLK, 512, 0, stream>>>(idx, E, flag, histB, NB, NBLK,
                                             binTotal, binned);
        k_sort2   <<<NB, 1024, 0, stream>>>(binned, binTotal, sortedS,
                                            rowPtr, N, NB);
        k_nodesum <<<(N * TPN + 511) / 512, 512, 0, stream>>>(sortedS, rowPtr,
                                                              ssrc_h, strg_f,
                                                              combo, N);
        k_edge_out_c <<<(E + 255) / 256, 256, 0, stream>>>(idx, E, ssrc_h, combo,
                                                           flag, out);
    } else {
        // ---- minimal fallback layout (~11 MB) -----------------------------
        size_t o2 = 0;
        auto alloc2 = [&](size_t bytes) { size_t o = o2; o2 = (o2 + bytes + 255) & ~(size_t)255; return o; };
        unsigned int* fb_flag = (unsigned int*)(ws + alloc2(8));
        float*        fb_Wc   = (float*)(ws + alloc2(NOUT * D_IN * sizeof(float)));
        float*        fb_sums = (float*)(ws + alloc2(NHb));
        float*        fb_ssrc = (float*)(ws + alloc2(NHb));
        float*        fb_strg = (float*)(ws + alloc2(NHb));

        hipMemsetAsync(fb_sums, 0, NHb, stream);
        k_fold_w <<<(D_IN * HEADS + 255) / 256, 256, 0, stream>>>(W, a_src, a_trg,
                                                                  fb_Wc, fb_flag,
                                                                  (int*)nullptr, 0);
        k_detect_fb <<<128, 256, 0, stream>>>(idx, dwords, fb_flag);
        k_scores_fb <<<(N + SROWS - 1) / SROWS, 256, 0, stream>>>(x, fb_Wc, fb_ssrc,
                                                                  fb_strg, N);
        int eblocks = (E + 255) / 256;
        k_edge_sum <<<eblocks, 256, 0, stream>>>(idx, E, fb_ssrc, fb_strg, fb_sums,
                                                 fb_flag);
        k_edge_out <<<eblocks, 256, 0, stream>>>(idx, E, fb_ssrc, fb_strg, fb_sums,
                                                 fb_flag, out);
    }
}

// Round 17
// 212.048 us; speedup vs baseline: 1.1623x; 1.1623x over previous
//
#include <hip/hip_runtime.h>
#include <hip/hip_fp16.h>

#define D_IN   128
#define HEADS  8
#define FOUT   64
#define NOUT   16     // 8 src + 8 trg folded outputs
#define NPB    512    // nodes per bin (local index 9 bits; src 20 + local 9 = 29 bits)
#define NPB_SH 9
#define NB_MAX 1024   // max bins
#define CHUNK  8192   // edges per histogram/scatter block (~42 edges/bin/block -> full lines)
#define NBLK_MAX 1024 // max blocks in pass A/C (scan width)
#define TPN    8      // threads per node in k_nodesum
#define SROWS  64     // nodes per k_scores tile
#define SPAD   129    // padded LDS row stride (floats)
#define DET_BLOCKS 128

typedef unsigned __attribute__((ext_vector_type(2))) uint2v;
typedef float    __attribute__((ext_vector_type(4))) float4v;

// -------------------------------- helpers -----------------------------------
__device__ __forceinline__ unsigned pack2(float a, float b) {
    union { __half2 h; unsigned u; } c;
    c.h = __floats2half2_rn(a, b);
    return c.u;
}
__device__ __forceinline__ float2 up2(unsigned u) {
    union { unsigned x; __half2 h; } c;
    c.x = u;
    return __half22float2(c.h);
}

// Non-temporal ONLY for dense read-once (idx, x) and dense write-once (out)
// streams. NEVER for scattered stores or producer->consumer intermediates
// (r8: nt scattered stores defeat L2 write-combining, 13->89 MB writes).
__device__ __forceinline__ unsigned ntl_u(const unsigned* p) {
    return __builtin_nontemporal_load(p);
}
__device__ __forceinline__ uint2v ntl_u2(const unsigned* p) {
    return __builtin_nontemporal_load((const uint2v*)p);
}
__device__ __forceinline__ float4v ntl_f4(const float* p) {
    return __builtin_nontemporal_load((const float4v*)p);
}
__device__ __forceinline__ void nts_f4(float* p, float4v v) {
    __builtin_nontemporal_store(v, (float4v*)p);
}

__device__ __forceinline__ void load_edge(const unsigned int* idx, int e, int E,
                                          bool is64, unsigned int& s, unsigned int& t) {
    if (is64) {
        uint2v a = ntl_u2(idx + 2 * (size_t)e);
        uint2v b = ntl_u2(idx + 2 * ((size_t)E + e));
        s = a.x; t = b.x;
    } else {
        s = ntl_u(idx + e);
        t = ntl_u(idx + (size_t)E + e);
    }
}

// ---------------------------------------------------------------------------
// Fold scoring vectors into projection (Wc [16][128]); zero flag + binTotal.
// (A 4B hipMemsetAsync cost ~60us/replay as a fillBufferAligned dispatch - r7.)
__global__ void k_fold_w(const float* __restrict__ W,
                         const float* __restrict__ a_src,
                         const float* __restrict__ a_trg,
                         float* __restrict__ Wc,
                         unsigned int* __restrict__ flag,
                         int* __restrict__ binTotal, int NB) {
    int t = blockIdx.x * blockDim.x + threadIdx.x;
    if (t == 0) flag[0] = 0u;
    if (binTotal && t < NB) binTotal[t] = 0;
    if (t >= D_IN * HEADS) return;
    int d = t >> 3, h = t & 7;
    const float* wrow = W + d * (HEADS * FOUT) + h * FOUT;
    float s1 = 0.f, s2 = 0.f;
    #pragma unroll 4
    for (int f = 0; f < FOUT; ++f) {
        float w = wrow[f];
        s1 += w * a_src[h * FOUT + f];
        s2 += w * a_trg[h * FOUT + f];
    }
    Wc[h * D_IN + d]           = s1;
    Wc[(HEADS + h) * D_IN + d] = s2;
}

// ---------------------------------------------------------------------------
// FUSED: per-node scores (shuffle-free, r7) + per-chunk histogram (blocks
// < NBLK) + sampled global int64/int32 detection (blocks < DET_BLOCKS).
// Hist decides the layout BLOCK-LOCALLY from the first 64 odd words of idx
// (all zero <=> int64 high-halves), so hist's idx read overlaps scores' x read.
__global__ void k_scores_h(const float* __restrict__ x,
                           const float* __restrict__ Wc,
                           float* __restrict__ strg_f,
                           __half* __restrict__ ssrc_h, int N,
                           const unsigned int* __restrict__ idx, int E,
                           int dwords, unsigned int* __restrict__ flag,
                           int* __restrict__ histB, int NB, int NBLK,
                           int* __restrict__ binTotal) {
    int tid = threadIdx.x;

    // --- global detection sample (for later kernels: scatter, edge_out) ---
    if ((int)blockIdx.x < DET_BLOCKS) {
        unsigned int local = 0;
        int stride = DET_BLOCKS * 256;
        for (int i = blockIdx.x * 256 + tid; 2 * i + 1 < dwords; i += stride)
            local |= idx[2 * i + 1];
        if (__any(local != 0) && (tid & 63) == 0)
            atomicOr(flag, 1u);
    }

    // --- histogram chunk (blocks < NBLK); barriers are block-uniform ------
    if ((int)blockIdx.x < NBLK) {
        __shared__ int h[NB_MAX];
        __shared__ int s_i32;
        if (tid == 0) s_i32 = 0;
        for (int i = tid; i < NB; i += blockDim.x) h[i] = 0;
        __syncthreads();
        if (tid < 64) {
            unsigned int v = (2 * tid + 1 < 2 * E) ? idx[2 * tid + 1] : 0u;
            if (__any(v != 0) && tid == 0) s_i32 = 1;
        }
        __syncthreads();
        bool is64 = (s_i32 == 0);

        int base = blockIdx.x * CHUNK;
        int lim  = min(base + CHUNK, E);
        for (int e = base + tid; e < lim; e += blockDim.x) {
            unsigned int t = is64 ? ntl_u2(idx + 2 * ((size_t)E + e)).x
                                  : ntl_u(idx + (size_t)E + e);
            atomicAdd(&h[t >> NPB_SH], 1);
        }
        __syncthreads();
        for (int i = tid; i < NB; i += blockDim.x) {
            histB[(size_t)i * NBLK + blockIdx.x] = h[i];
            if (h[i]) atomicAdd(&binTotal[i], h[i]);
        }
        __syncthreads();
    }

    // --- per-node scores --------------------------------------------------
    __shared__ float xt[SROWS * SPAD];
    int node0 = blockIdx.x * SROWS;
    int nrows = min(SROWS, N - node0);
    if (nrows <= 0) return;

    for (int i = tid; i < nrows * 32; i += 256) {
        int r = i >> 5, c = (i & 31) * 4;
        float4v v = ntl_f4(x + (size_t)(node0 + r) * D_IN + c);
        float* dst = &xt[r * SPAD + c];
        dst[0] = v.x; dst[1] = v.y; dst[2] = v.z; dst[3] = v.w;
    }
    __syncthreads();

    int r  = tid & 63;
    int og = tid >> 6;          // wave-uniform output group (4 outputs)
    if (r >= nrows) return;
    int n = node0 + r;

    const float* w = Wc + og * 4 * D_IN;
    float a0 = 0.f, a1 = 0.f, a2 = 0.f, a3 = 0.f;
    const float* xr = &xt[r * SPAD];
    #pragma unroll 8
    for (int d = 0; d < D_IN; ++d) {
        float xv = xr[d];
        a0 += xv * w[d];
        a1 += xv * w[D_IN + d];
        a2 += xv * w[2 * D_IN + d];
        a3 += xv * w[3 * D_IN + d];
    }

    if (og < 2) {
        uint2 hp;
        hp.x = pack2(a0, a1);
        hp.y = pack2(a2, a3);
        *(uint2*)(ssrc_h + (size_t)n * HEADS + og * 4) = hp;
    } else {
        *(float4*)(strg_f + (size_t)n * HEADS + (og - 2) * 4) =
            make_float4(a0, a1, a2, a3);
    }
}

// Pass B (fused, parallel): blocks 0..NB-1 scan histB rows -> exclusive histA
// offsets; block NB scans binTotal -> binBase. (Keeping this as its own
// dispatch: r16's self-scanning scatter serialized the prefix work per block
// and regressed 30->72us. A ~5us dispatch is only worth removing if its work
// stays parallel.) Rounds capped at ceil-log2(width).
__global__ void k_scan(const int* __restrict__ histB,
                       int* __restrict__ histA, int NB, int NBLK,
                       const int* __restrict__ binTotal,
                       int* __restrict__ binBase) {
    int b = blockIdx.x;
    int tid = threadIdx.x;
    if (b < NB) {
        __shared__ int v[NBLK_MAX];
        v[tid] = (tid < NBLK) ? histB[(size_t)b * NBLK + tid] : 0;
        __syncthreads();
        int w = 1; while (w < NBLK) w <<= 1;
        for (int off = 1; off < w; off <<= 1) {
            int t = (tid >= off) ? v[tid - off] : 0;
            __syncthreads();
            v[tid] += t;
            __syncthreads();
        }
        if (tid < NBLK)
            histA[(size_t)tid * NB + b] = tid ? v[tid - 1] : 0;
    } else {
        __shared__ int v2[NB_MAX];
        v2[tid] = (tid < NB) ? binTotal[tid] : 0;
        __syncthreads();
        int w = 1; while (w < NB) w <<= 1;
        for (int off = 1; off < w; off <<= 1) {
            int t = (tid >= off) ? v2[tid - off] : 0;
            __syncthreads();
            v2[tid] += t;
            __syncthreads();
        }
        if (tid < NB)
            binBase[tid] = tid ? v2[tid - 1] : 0;
    }
}

// Pass C: scatter packed edge records into bin order.
// record = src | (trg & 511) << 20   (needs N < 2^20)
__global__ void k_scatter(const unsigned int* __restrict__ idx, int E,
                          const unsigned int* __restrict__ flag,
                          const int* __restrict__ histA, int NB,
                          const int* __restrict__ binBase,
                          unsigned int* __restrict__ binned) {
    __shared__ int cnt[NB_MAX];
    for (int i = threadIdx.x; i < NB; i += blockDim.x)
        cnt[i] = binBase[i] + histA[(size_t)blockIdx.x * NB + i];
    __syncthreads();
    bool is64 = (*flag == 0u);
    int base = blockIdx.x * CHUNK;
    int lim  = min(base + CHUNK, E);
    for (int e = base + threadIdx.x; e < lim; e += blockDim.x) {
        unsigned int s, t;
        load_edge(idx, e, E, is64, s, t);
        int pos = atomicAdd(&cnt[t >> NPB_SH], 1);
        binned[pos] = s | ((t & (NPB - 1u)) << 20);
    }
}

// Pass D: per-bin counting sort by low 9 target bits -> CSR. 1024 threads.
// Not fused with nodesum (r11: 196-block fusion -> 14% occupancy -> 76us).
__global__ void k_sort2(const unsigned int* __restrict__ binned,
                        const int* __restrict__ binBase,
                        const int* __restrict__ binTotal,
                        unsigned int* __restrict__ sortedSrc,
                        int* __restrict__ rowPtr, int N, int NB) {
    __shared__ int cnt[NPB];
    __shared__ int scn[NPB];
    int b = blockIdx.x;
    int node0 = b << NPB_SH;
    int start = binBase[b], total = binTotal[b];
    int i = threadIdx.x;
    int T = blockDim.x;

    if (i < NPB) cnt[i] = 0;
    __syncthreads();
    for (int e = i; e < total; e += T)
        atomicAdd(&cnt[binned[start + e] >> 20], 1);
    __syncthreads();

    if (i < NPB) scn[i] = cnt[i];
    __syncthreads();
    for (int o = 1; o < NPB; o <<= 1) {
        int t = (i < NPB && i >= o) ? scn[i - o] : 0;
        __syncthreads();
        if (i < NPB) scn[i] += t;
        __syncthreads();
    }
    if (i < NPB) {
        int excl = scn[i] - cnt[i];
        cnt[i] = excl;
        int n = node0 + i;
        if (n < N) rowPtr[n] = start + excl;
    }
    if (b == NB - 1 && i == 0) rowPtr[N] = start + total;
    __syncthreads();

    for (int e = i; e < total; e += T) {
        unsigned int v = binned[start + e];
        int pos = atomicAdd(&cnt[v >> 20], 1);
        sortedSrc[start + pos] = v & 0xFFFFFu;
    }
}

// ---------------------------------------------------------------------------
// Pass E: per-node sums via contiguous edge runs (full-occupancy grid);
// emits fused combo record { strg half[8], 1/sum half[8] }.
__global__ void k_nodesum(const unsigned int* __restrict__ sortedSrc,
                          const int* __restrict__ rowPtr,
                          const __half* __restrict__ ssrc_h,
                          const float* __restrict__ strg_f,
                          __half* __restrict__ combo, int N) {
    int gt = blockIdx.x * blockDim.x + threadIdx.x;
    int n  = gt >> 3;           // TPN = 8
    int k  = gt & (TPN - 1);
    if (n >= N) return;

    int r0 = rowPtr[n], r1 = rowPtr[n + 1];
    const float4* tp = (const float4*)(strg_f + (size_t)n * HEADS);
    float4 ta = tp[0], tb = tp[1];
    float st[8] = { ta.x, ta.y, ta.z, ta.w, tb.x, tb.y, tb.z, tb.w };
    float acc[8] = { 0, 0, 0, 0, 0, 0, 0, 0 };

    for (int e = r0 + k; e < r1; e += TPN) {
        unsigned int s = sortedSrc[e];
        uint4 sv = *(const uint4*)(ssrc_h + (size_t)s * HEADS);
        float2 f01 = up2(sv.x), f23 = up2(sv.y), f45 = up2(sv.z), f67 = up2(sv.w);
        float vs[8] = { f01.x, f01.y, f23.x, f23.y, f45.x, f45.y, f67.x, f67.y };
        #pragma unroll
        for (int h = 0; h < HEADS; ++h) {
            float sc = vs[h] + st[h];
            sc = sc > 0.f ? sc : 0.2f * sc;
            acc[h] += expf(sc);
        }
    }
    #pragma unroll
    for (int h = 0; h < HEADS; ++h) {
        acc[h] += __shfl_xor(acc[h], 1, 64);
        acc[h] += __shfl_xor(acc[h], 2, 64);
        acc[h] += __shfl_xor(acc[h], 4, 64);
    }
    if (k == 0) {
        float rs[8];
        #pragma unroll
        for (int h = 0; h < HEADS; ++h) rs[h] = 1.0f / (acc[h] + 1e-16f);
        uint4 c0, c1;
        c0.x = pack2(st[0], st[1]);  c0.y = pack2(st[2], st[3]);
        c0.z = pack2(st[4], st[5]);  c0.w = pack2(st[6], st[7]);
        c1.x = pack2(rs[0], rs[1]);  c1.y = pack2(rs[2], rs[3]);
        c1.z = pack2(rs[4], rs[5]);  c1.w = pack2(rs[6], rs[7]);
        uint4* cp = (uint4*)(combo + (size_t)n * 16);
        cp[0] = c0;
        cp[1] = c1;
    }
}

// ---------------------------------------------------------------------------
// Fast edge output (r12 single-edge form, measured best at 65.0us; dual-edge
// variants regressed twice - r10: 67, r15: 66.5. One edge/thread = max TLP):
// 2 gathers (16B ssrc_h, 32B combo) over a 4.8 MB hot set; nt idx/out.
__global__ void k_edge_out_c(const unsigned int* __restrict__ idx, int E,
                             const __half* __restrict__ ssrc_h,
                             const __half* __restrict__ combo,
                             const unsigned int* __restrict__ flag,
                             float* __restrict__ out) {
    int e = blockIdx.x * blockDim.x + threadIdx.x;
    if (e >= E) return;
    bool is64 = (*flag == 0u);
    unsigned int s, t;
    load_edge(idx, e, E, is64, s, t);

    uint4 sv = *(const uint4*)(ssrc_h + (size_t)s * HEADS);
    const uint4* cp = (const uint4*)(combo + (size_t)t * 16);
    uint4 c0 = cp[0], c1 = cp[1];

    float2 s01 = up2(sv.x), s23 = up2(sv.y), s45 = up2(sv.z), s67 = up2(sv.w);
    float2 t01 = up2(c0.x), t23 = up2(c0.y), t45 = up2(c0.z), t67 = up2(c0.w);
    float2 r01 = up2(c1.x), r23 = up2(c1.y), r45 = up2(c1.z), r67 = up2(c1.w);

    float ss[8] = { s01.x, s01.y, s23.x, s23.y, s45.x, s45.y, s67.x, s67.y };
    float st[8] = { t01.x, t01.y, t23.x, t23.y, t45.x, t45.y, t67.x, t67.y };
    float rs[8] = { r01.x, r01.y, r23.x, r23.y, r45.x, r45.y, r67.x, r67.y };

    float o[8];
    #pragma unroll
    for (int h = 0; h < HEADS; ++h) {
        float sc = ss[h] + st[h];
        sc = sc > 0.f ? sc : 0.2f * sc;
        o[h] = expf(sc) * rs[h];
    }
    float4v o0 = { o[0], o[1], o[2], o[3] };
    float4v o1 = { o[4], o[5], o[6], o[7] };
    nts_f4(out + (size_t)e * HEADS,     o0);
    nts_f4(out + (size_t)e * HEADS + 4, o1);
}

// ---------------------------------------------------------------------------
// Fallback path (device atomics + fp32), used only if workspace too small.
__device__ __forceinline__ void edge_scores(const float* ssrc, const float* strg,
                                            unsigned int s, unsigned int t, float* ex) {
    const float4* sp = (const float4*)(ssrc + (size_t)s * HEADS);
    const float4* tp = (const float4*)(strg + (size_t)t * HEADS);
    float4 sa = sp[0], sb = sp[1], ta = tp[0], tb = tp[1];
    float v[8] = { sa.x + ta.x, sa.y + ta.y, sa.z + ta.z, sa.w + ta.w,
                   sb.x + tb.x, sb.y + tb.y, sb.z + tb.z, sb.w + tb.w };
    #pragma unroll
    for (int h = 0; h < HEADS; ++h) {
        float sc = v[h];
        sc = sc > 0.f ? sc : 0.2f * sc;
        ex[h] = expf(sc);
    }
}

__global__ void k_detect_fb(const unsigned int* __restrict__ idx_w, int nwords,
                            unsigned int* __restrict__ flag) {
    unsigned int local = 0;
    int stride = gridDim.x * blockDim.x;
    for (int i = blockIdx.x * blockDim.x + threadIdx.x; 2 * i + 1 < nwords; i += stride)
        local |= idx_w[2 * i + 1];
    if (__any(local != 0) && (threadIdx.x & 63) == 0)
        atomicOr(flag, 1u);
}

__global__ void k_scores_fb(const float* __restrict__ x,
                            const float* __restrict__ Wc,
                            float* __restrict__ ssrc_f,
                            float* __restrict__ strg_f, int N) {
    __shared__ float xt[SROWS * SPAD];
    int node0 = blockIdx.x * SROWS;
    int tid   = threadIdx.x;
    int nrows = min(SROWS, N - node0);

    for (int i = tid; i < nrows * 32; i += 256) {
        int r = i >> 5, c = (i & 31) * 4;
        float4v v = ntl_f4(x + (size_t)(node0 + r) * D_IN + c);
        float* dst = &xt[r * SPAD + c];
        dst[0] = v.x; dst[1] = v.y; dst[2] = v.z; dst[3] = v.w;
    }
    __syncthreads();

    int r  = tid & 63;
    int og = tid >> 6;
    if (r >= nrows) return;
    int n = node0 + r;

    const float* w = Wc + og * 4 * D_IN;
    float a0 = 0.f, a1 = 0.f, a2 = 0.f, a3 = 0.f;
    const float* xr = &xt[r * SPAD];
    #pragma unroll 8
    for (int d = 0; d < D_IN; ++d) {
        float xv = xr[d];
        a0 += xv * w[d];
        a1 += xv * w[D_IN + d];
        a2 += xv * w[2 * D_IN + d];
        a3 += xv * w[3 * D_IN + d];
    }
    float4 res = make_float4(a0, a1, a2, a3);
    if (og < 2) *(float4*)(ssrc_f + (size_t)n * HEADS + og * 4)       = res;
    else        *(float4*)(strg_f + (size_t)n * HEADS + (og - 2) * 4) = res;
}

__global__ void k_edge_sum(const unsigned int* __restrict__ idx, int E,
                           const float* __restrict__ ssrc,
                           const float* __restrict__ strg,
                           float* __restrict__ sums,
                           const unsigned int* __restrict__ flag) {
    int e = blockIdx.x * blockDim.x + threadIdx.x;
    if (e >= E) return;
    bool is64 = (*flag == 0u);
    unsigned int s, t;
    load_edge(idx, e, E, is64, s, t);
    float ex[8];
    edge_scores(ssrc, strg, s, t, ex);
    float* dst = sums + (size_t)t * HEADS;
    #pragma unroll
    for (int h = 0; h < HEADS; ++h)
        atomicAdd(dst + h, ex[h]);
}

__global__ void k_edge_out(const unsigned int* __restrict__ idx, int E,
                           const float* __restrict__ ssrc,
                           const float* __restrict__ strg,
                           const float* __restrict__ sums,
                           const unsigned int* __restrict__ flag,
                           float* __restrict__ out) {
    int e = blockIdx.x * blockDim.x + threadIdx.x;
    if (e >= E) return;
    bool is64 = (*flag == 0u);
    unsigned int s, t;
    load_edge(idx, e, E, is64, s, t);
    float ex[8];
    edge_scores(ssrc, strg, s, t, ex);
    const float4* sm = (const float4*)(sums + (size_t)t * HEADS);
    float4 m0 = sm[0], m1 = sm[1];
    float4 o0, o1;
    o0.x = ex[0] / (m0.x + 1e-16f);  o0.y = ex[1] / (m0.y + 1e-16f);
    o0.z = ex[2] / (m0.z + 1e-16f);  o0.w = ex[3] / (m0.w + 1e-16f);
    o1.x = ex[4] / (m1.x + 1e-16f);  o1.y = ex[5] / (m1.y + 1e-16f);
    o1.z = ex[6] / (m1.z + 1e-16f);  o1.w = ex[7] / (m1.w + 1e-16f);
    float4* op = (float4*)(out + (size_t)e * HEADS);
    op[0] = o0;
    op[1] = o1;
}

// ---------------------------------------------------------------------------
extern "C" void kernel_launch(void* const* d_in, const int* in_sizes, int n_in,
                              void* d_out, int out_size, void* d_ws, size_t ws_size,
                              hipStream_t stream) {
    const float*        x     = (const float*)d_in[0];
    const float*        W     = (const float*)d_in[1];
    const float*        a_src = (const float*)d_in[2];
    const float*        a_trg = (const float*)d_in[3];
    const unsigned int* idx   = (const unsigned int*)d_in[4];

    const int N  = in_sizes[0] / D_IN;   // 100000
    const int E  = in_sizes[4] / 2;      // 3200000
    const int NH = N * HEADS;
    const int NB   = (N + NPB - 1) / NPB;     // 196
    const int NBLK = (E + CHUNK - 1) / CHUNK; // 391

    float* out = (float*)d_out;
    char*  ws  = (char*)d_ws;
    size_t NHb = (size_t)NH * sizeof(float);

    // ---- fast-path layout -------------------------------------------------
    size_t off = 0;
    auto alloc = [&](size_t bytes) { size_t o = off; off = (off + bytes + 255) & ~(size_t)255; return o; };
    unsigned int* flag     = (unsigned int*)(ws + alloc(8));
    float*        strg_f   = (float*)(ws + alloc(NHb));
    __half*       ssrc_h   = (__half*)(ws + alloc((size_t)NH * sizeof(__half)));
    __half*       combo    = (__half*)(ws + alloc((size_t)N * 16 * sizeof(__half)));
    float*        Wc       = (float*)(ws + alloc(NOUT * D_IN * sizeof(float)));
    int*          histA    = (int*)(ws + alloc((size_t)NBLK * NB * sizeof(int)));
    int*          histB    = (int*)(ws + alloc((size_t)NB * NBLK * sizeof(int)));
    int*          binTotal = (int*)(ws + alloc((size_t)NB * sizeof(int)));
    int*          binBase  = (int*)(ws + alloc((size_t)NB * sizeof(int)));
    unsigned int* binned   = (unsigned int*)(ws + alloc((size_t)E * sizeof(unsigned int)));
    unsigned int* sortedS  = (unsigned int*)(ws + alloc((size_t)E * sizeof(unsigned int)));
    int*          rowPtr   = (int*)(ws + alloc((size_t)(N + 1) * sizeof(int)));

    const bool fast = (off <= ws_size) && (NB <= NB_MAX) && (NBLK <= NBLK_MAX)
                      && (N < (1 << 20));

    int dwords = in_sizes[4];
    if (dwords > (1 << 20)) dwords = 1 << 20;   // sampled detection is sufficient

    if (fast) {
        k_fold_w <<<(D_IN * HEADS + 255) / 256, 256, 0, stream>>>(W, a_src, a_trg, Wc,
                                                                  flag, binTotal, NB);
        k_scores_h <<<(N + SROWS - 1) / SROWS, 256, 0, stream>>>(x, Wc, strg_f,
                                                                 ssrc_h, N, idx, E,
                                                                 dwords, flag,
                                                                 histB, NB, NBLK,
                                                                 binTotal);
        k_scan    <<<NB + 1, NBLK_MAX, 0, stream>>>(histB, histA, NB, NBLK,
                                                    binTotal, binBase);
        k_scatter <<<NBLK, 512, 0, stream>>>(idx, E, flag, histA, NB, binBase,
                                             binned);
        k_sort2   <<<NB, 1024, 0, stream>>>(binned, binBase, binTotal, sortedS,
                                            rowPtr, N, NB);
        k_nodesum <<<(N * TPN + 511) / 512, 512, 0, stream>>>(sortedS, rowPtr,
                                                              ssrc_h, strg_f,
                                                              combo, N);
        k_edge_out_c <<<(E + 255) / 256, 256, 0, stream>>>(idx, E, ssrc_h, combo,
                                                           flag, out);
    } else {
        // ---- minimal fallback layout (~11 MB) -----------------------------
        size_t o2 = 0;
        auto alloc2 = [&](size_t bytes) { size_t o = o2; o2 = (o2 + bytes + 255) & ~(size_t)255; return o; };
        unsigned int* fb_flag = (unsigned int*)(ws + alloc2(8));
        float*        fb_Wc   = (float*)(ws + alloc2(NOUT * D_IN * sizeof(float)));
        float*        fb_sums = (float*)(ws + alloc2(NHb));
        float*        fb_ssrc = (float*)(ws + alloc2(NHb));
        float*        fb_strg = (float*)(ws + alloc2(NHb));

        hipMemsetAsync(fb_sums, 0, NHb, stream);
        k_fold_w <<<(D_IN * HEADS + 255) / 256, 256, 0, stream>>>(W, a_src, a_trg,
                                                                  fb_Wc, fb_flag,
                                                                  (int*)nullptr, 0);
        k_detect_fb <<<128, 256, 0, stream>>>(idx, dwords, fb_flag);
        k_scores_fb <<<(N + SROWS - 1) / SROWS, 256, 0, stream>>>(x, fb_Wc, fb_ssrc,
                                                                  fb_strg, N);
        int eblocks = (E + 255) / 256;
        k_edge_sum <<<eblocks, 256, 0, stream>>>(idx, E, fb_ssrc, fb_strg, fb_sums,
                                                 fb_flag);
        k_edge_out <<<eblocks, 256, 0, stream>>>(idx, E, fb_ssrc, fb_strg, fb_sums,
                                                 fb_flag, out);
    }
}